// Round 1
// 209.930 us; speedup vs baseline: 1.1378x; 1.1378x over previous
//
#include <hip/hip_runtime.h>
#include <hip/hip_bf16.h>

#define N_NODES 100000
#define N_EDGES 1600000
#define IN_DIM 128
#define HID 64
#define NB ((N_NODES + 255) / 256)          // 391 buckets of 256 dst nodes
#define EPB 4096                            // edges per k_bucket block
#define BUCKET_BLOCKS ((N_EDGES + EPB - 1) / EPB)  // 391
#define MAXPB 8192                          // fixed gbuf region per bucket (mean 4092)

// ---------------- threefry2x32, key = (0, 42) ----------------
__device__ __forceinline__ unsigned rotl32(unsigned x, unsigned r) {
    return (x << r) | (x >> (32u - r));
}

__device__ __forceinline__ void threefry2x32_k42(unsigned x0, unsigned x1,
                                                 unsigned& o0, unsigned& o1) {
    const unsigned ks0 = 0u;
    const unsigned ks1 = 42u;
    const unsigned ks2 = 0u ^ 42u ^ 0x1BD11BDAu;
    x0 += ks0; x1 += ks1;
    x0 += x1; x1 = rotl32(x1, 13); x1 ^= x0;
    x0 += x1; x1 = rotl32(x1, 15); x1 ^= x0;
    x0 += x1; x1 = rotl32(x1, 26); x1 ^= x0;
    x0 += x1; x1 = rotl32(x1, 6);  x1 ^= x0;
    x0 += ks1; x1 += ks2 + 1u;
    x0 += x1; x1 = rotl32(x1, 17); x1 ^= x0;
    x0 += x1; x1 = rotl32(x1, 29); x1 ^= x0;
    x0 += x1; x1 = rotl32(x1, 16); x1 ^= x0;
    x0 += x1; x1 = rotl32(x1, 24); x1 ^= x0;
    x0 += ks2; x1 += ks0 + 2u;
    x0 += x1; x1 = rotl32(x1, 13); x1 ^= x0;
    x0 += x1; x1 = rotl32(x1, 15); x1 ^= x0;
    x0 += x1; x1 = rotl32(x1, 26); x1 ^= x0;
    x0 += x1; x1 = rotl32(x1, 6);  x1 ^= x0;
    x0 += ks0; x1 += ks1 + 3u;
    x0 += x1; x1 = rotl32(x1, 17); x1 ^= x0;
    x0 += x1; x1 = rotl32(x1, 29); x1 ^= x0;
    x0 += x1; x1 = rotl32(x1, 16); x1 ^= x0;
    x0 += x1; x1 = rotl32(x1, 24); x1 ^= x0;
    x0 += ks1; x1 += ks2 + 4u;
    x0 += x1; x1 = rotl32(x1, 13); x1 ^= x0;
    x0 += x1; x1 = rotl32(x1, 15); x1 ^= x0;
    x0 += x1; x1 = rotl32(x1, 26); x1 ^= x0;
    x0 += x1; x1 = rotl32(x1, 6);  x1 ^= x0;
    x0 += ks2; x1 += ks0 + 5u;
    o0 = x0; o1 = x1;
}

__device__ __forceinline__ float bf2f(unsigned short u) {
    return __uint_as_float((unsigned)u << 16);
}
// low/high bf16 of a packed uint
__device__ __forceinline__ float bf2f_lo(unsigned u) {
    return __uint_as_float(u << 16);
}
__device__ __forceinline__ float bf2f_hi(unsigned u) {
    return __uint_as_float(u & 0xffff0000u);
}

// ---- phase 1: bucketed scatter into FIXED regions (no scan dependency) ----
// record = (c & 255) << 17 | r   (r < 2^17)
__global__ __launch_bounds__(512) void k_bucket(const int* __restrict__ src,
                                                const int* __restrict__ dst,
                                                int* __restrict__ bucketcnt,
                                                unsigned* __restrict__ gbuf) {
    __shared__ int cnt[512];
    __shared__ int off[512];
    __shared__ int cur[NB];
    __shared__ int gbase[NB];
    __shared__ unsigned buf[EPB];
    __shared__ unsigned short bkt[EPB];
    const int t = threadIdx.x;
    const int e0 = blockIdx.x * EPB;
    const int n = min(EPB, N_EDGES - e0);
    cnt[t] = 0;
    __syncthreads();
    unsigned myrec[EPB / 512];
    int myb[EPB / 512];
#pragma unroll
    for (int k = 0; k < EPB / 512; k++) {
        int e = e0 + k * 512 + t;
        if (e < N_EDGES) {
            int r = src[e];
            int c = dst[e];
            int b = c >> 8;
            myrec[k] = ((unsigned)(c & 255) << 17) | (unsigned)r;
            myb[k] = b;
            atomicAdd(&cnt[b], 1);
        } else {
            myb[k] = -1;
        }
    }
    __syncthreads();
    int own = cnt[t];
    for (int o = 1; o < 512; o <<= 1) {
        int v = (t >= o) ? cnt[t - o] : 0;
        __syncthreads();
        cnt[t] += v;
        __syncthreads();
    }
    off[t] = cnt[t] - own;  // exclusive prefix (records sorted by bucket in buf)
    if (t < NB) {
        cur[t] = off[t];
        gbase[t] = t * MAXPB + (own ? atomicAdd(&bucketcnt[t], own) : 0);
    }
    __syncthreads();
#pragma unroll
    for (int k = 0; k < EPB / 512; k++) {
        if (myb[k] >= 0) {
            int p = atomicAdd(&cur[myb[k]], 1);
            buf[p] = myrec[k];
            bkt[p] = (unsigned short)myb[k];
        }
    }
    __syncthreads();
    for (int j = t; j < n; j += 512) {
        int b = bkt[j];
        gbuf[gbase[b] + (j - off[b])] = buf[j];
    }
}

// ---- exclusive scan over NB bucket totals -> bucket_base ----
__global__ __launch_bounds__(512) void k_scanB(const int* __restrict__ bucketcnt,
                                               int* __restrict__ bucket_base) {
    __shared__ int s[512];
    int t = threadIdx.x;
    int own = (t < NB) ? bucketcnt[t] : 0;
    s[t] = own;
    __syncthreads();
    for (int o = 1; o < 512; o <<= 1) {
        int v = (t >= o) ? s[t - o] : 0;
        __syncthreads();
        s[t] += v;
        __syncthreads();
    }
    if (t < NB) bucket_base[t] = s[t] - own;
    if (t == 511) bucket_base[NB] = s[511];  // = N_EDGES
}

// ---- phase 2: per-bucket count + scan + row_start + dinv + distribute ----
__global__ __launch_bounds__(256) void k_csr2(const unsigned* __restrict__ gbuf,
                                              const int* __restrict__ bucketcnt,
                                              const int* __restrict__ bucket_base,
                                              int* __restrict__ row_start,
                                              float* __restrict__ dinv,
                                              int* __restrict__ srcs) {
    __shared__ unsigned lbuf[MAXPB];  // 32 KB
    __shared__ int lcnt[256];
    __shared__ int pre[256];
    __shared__ int cur[256];
    const int b = blockIdx.x, t = threadIdx.x;
    const int n = bucketcnt[b];
    const unsigned* reg = gbuf + (size_t)b * MAXPB;
    lcnt[t] = 0;
    for (int j = t; j < n; j += 256) lbuf[j] = reg[j];
    __syncthreads();
    for (int j = t; j < n; j += 256) atomicAdd(&lcnt[lbuf[j] >> 17], 1);
    __syncthreads();
    int my = lcnt[t];
    pre[t] = my;
    __syncthreads();
    for (int o = 1; o < 256; o <<= 1) {
        int v = (t >= o) ? pre[t - o] : 0;
        __syncthreads();
        pre[t] += v;
        __syncthreads();
    }
    const int gb = bucket_base[b];
    int base = gb + pre[t] - my;  // global exclusive prefix
    cur[t] = base;
    const int c = b * 256 + t;
    if (c < N_NODES) {
        row_start[c] = base;
        dinv[c] = rsqrtf((float)(my + 1));  // in-degree + self-loop
    }
    if (b == NB - 1 && t == 255) row_start[N_NODES] = gb + pre[255];
    __syncthreads();
    for (int j = t; j < n; j += 256) {
        unsigned rec = lbuf[j];
        int pos = atomicAdd(&cur[rec >> 17], 1);
        srcs[pos] = (int)(rec & 0x1FFFF);
    }
}

// ------ g = (x @ W_conv) * dinv[row], bf16 out; W column in registers ------
__global__ __launch_bounds__(256) void k_gemm(const float* __restrict__ x,
                                              const float* __restrict__ W,
                                              const float* __restrict__ dinv,
                                              unsigned short* __restrict__ gm) {
    __shared__ float Wl[IN_DIM * HID];  // 32 KB
    __shared__ float xs[16][IN_DIM];    // 8 KB
    const int t = threadIdx.x;
    const float4* W4 = (const float4*)W;
    for (int i = t; i < IN_DIM * HID / 4; i += 256) ((float4*)Wl)[i] = W4[i];
    const int base = blockIdx.x * 16;
    const float4* x4 = (const float4*)(x + (size_t)base * IN_DIM);
    for (int i = t; i < 16 * IN_DIM / 4; i += 256) ((float4*)xs)[i] = x4[i];
    __syncthreads();
    const int d = t & 63, g = t >> 6;
    float wreg[IN_DIM];
#pragma unroll
    for (int k = 0; k < IN_DIM; k++) wreg[k] = Wl[k * HID + d];
    float a0 = 0.f, a1 = 0.f, a2 = 0.f, a3 = 0.f;
#pragma unroll
    for (int k = 0; k < IN_DIM; k += 4) {
        float4 xv0 = *(const float4*)&xs[g][k];
        float4 xv1 = *(const float4*)&xs[g + 4][k];
        float4 xv2 = *(const float4*)&xs[g + 8][k];
        float4 xv3 = *(const float4*)&xs[g + 12][k];
        a0 += xv0.x * wreg[k] + xv0.y * wreg[k + 1] + xv0.z * wreg[k + 2] + xv0.w * wreg[k + 3];
        a1 += xv1.x * wreg[k] + xv1.y * wreg[k + 1] + xv1.z * wreg[k + 2] + xv1.w * wreg[k + 3];
        a2 += xv2.x * wreg[k] + xv2.y * wreg[k + 1] + xv2.z * wreg[k + 2] + xv2.w * wreg[k + 3];
        a3 += xv3.x * wreg[k] + xv3.y * wreg[k + 1] + xv3.z * wreg[k + 2] + xv3.w * wreg[k + 3];
    }
    a0 *= dinv[base + g];
    a1 *= dinv[base + g + 4];
    a2 *= dinv[base + g + 8];
    a3 *= dinv[base + g + 12];
    gm[(size_t)(base + g) * HID + d]      = __bfloat16_as_ushort(__float2bfloat16(a0));
    gm[(size_t)(base + g + 4) * HID + d]  = __bfloat16_as_ushort(__float2bfloat16(a1));
    gm[(size_t)(base + g + 8) * HID + d]  = __bfloat16_as_ushort(__float2bfloat16(a2));
    gm[(size_t)(base + g + 12) * HID + d] = __bfloat16_as_ushort(__float2bfloat16(a3));
}

// ------- fused gather(bf16 g) + self + bias/relu/dropout + [64->2] matvec -------
// v2: 16 lanes per dst node (4 dims/lane, dwordx2 gathers), 4 dsts per wave,
//     16 dsts per block. 4 independent edge streams/wave * unroll-8 => high MLP.
//     srcs indices software-pipelined so index->gather dependency is hidden.
__global__ __launch_bounds__(256, 4) void k_aggr(const unsigned short* __restrict__ gm,
                                                 const int* __restrict__ row_start,
                                                 const int* __restrict__ srcs,
                                                 const float* __restrict__ dinv,
                                                 const float* __restrict__ bconv,
                                                 const float* __restrict__ Wlin,
                                                 const float* __restrict__ blin,
                                                 float* __restrict__ out) {
    const int c  = blockIdx.x * 16 + (threadIdx.x >> 4);  // dst node, group of 16 lanes
    const int d4 = threadIdx.x & 15;                      // dim quad: dims [4*d4, 4*d4+4)
    const int beg = row_start[c];
    const int end = row_start[c + 1];

    // self-loop term g[c] (accumulation order identical to v1: self first, then j asc)
    const uint2 s0 = *(const uint2*)(gm + ((size_t)c << 6) + (d4 << 2));
    float a0 = bf2f_lo(s0.x), a1 = bf2f_hi(s0.x);
    float a2 = bf2f_lo(s0.y), a3 = bf2f_hi(s0.y);

    int j = beg;
    if (j + 8 <= end) {
        int r[8];
#pragma unroll
        for (int u = 0; u < 8; u++) r[u] = srcs[j + u];
        while (true) {
            uint2 w[8];
#pragma unroll
            for (int u = 0; u < 8; u++)
                w[u] = *(const uint2*)(gm + ((size_t)r[u] << 6) + (d4 << 2));
            j += 8;
            const bool more = (j + 8 <= end);
            int r2[8];
            if (more) {
#pragma unroll
                for (int u = 0; u < 8; u++) r2[u] = srcs[j + u];
            }
#pragma unroll
            for (int u = 0; u < 8; u++) {
                a0 += bf2f_lo(w[u].x); a1 += bf2f_hi(w[u].x);
                a2 += bf2f_lo(w[u].y); a3 += bf2f_hi(w[u].y);
            }
            if (!more) break;
#pragma unroll
            for (int u = 0; u < 8; u++) r[u] = r2[u];
        }
    }
    for (; j < end; j++) {
        const int r = srcs[j];
        const uint2 w = *(const uint2*)(gm + ((size_t)r << 6) + (d4 << 2));
        a0 += bf2f_lo(w.x); a1 += bf2f_hi(w.x);
        a2 += bf2f_lo(w.y); a3 += bf2f_hi(w.y);
    }

    const float dv = dinv[c];
    const float4 bc4 = *(const float4*)(bconv + (d4 << 2));
    float v0 = fmaxf(a0 * dv + bc4.x, 0.f);
    float v1 = fmaxf(a1 * dv + bc4.y, 0.f);
    float v2 = fmaxf(a2 * dv + bc4.z, 0.f);
    float v3 = fmaxf(a3 * dv + bc4.w, 0.f);

    // dropout: same per-element threefry mapping as v1 (i = c*64 + d)
    const unsigned ib = (unsigned)(c * HID + (d4 << 2));
    unsigned o0, o1;
    threefry2x32_k42(0u, ib + 0u, o0, o1);
    v0 = ((o0 ^ o1) & 0x80000000u) ? 0.f : v0 * 2.f;
    threefry2x32_k42(0u, ib + 1u, o0, o1);
    v1 = ((o0 ^ o1) & 0x80000000u) ? 0.f : v1 * 2.f;
    threefry2x32_k42(0u, ib + 2u, o0, o1);
    v2 = ((o0 ^ o1) & 0x80000000u) ? 0.f : v2 * 2.f;
    threefry2x32_k42(0u, ib + 3u, o0, o1);
    v3 = ((o0 ^ o1) & 0x80000000u) ? 0.f : v3 * 2.f;

    // [64 -> 2] matvec partials: Wlin row-major [64][2]; lane covers rows 4*d4..4*d4+3
    const float4 wl0 = *(const float4*)(Wlin + (d4 << 3));      // rows 4d4, 4d4+1
    const float4 wl1 = *(const float4*)(Wlin + (d4 << 3) + 4);  // rows 4d4+2, 4d4+3
    float p0 = v0 * wl0.x + v1 * wl0.z + v2 * wl1.x + v3 * wl1.z;
    float p1 = v0 * wl0.y + v1 * wl0.w + v2 * wl1.y + v3 * wl1.w;

    // reduce across the 16 lanes of this dst group (aligned, so xor stays in-group)
#pragma unroll
    for (int off = 8; off; off >>= 1) {
        p0 += __shfl_xor(p0, off);
        p1 += __shfl_xor(p1, off);
    }
    if (d4 == 0) {
        *(float2*)(out + (size_t)c * 2) = make_float2(p0 + blin[0], p1 + blin[1]);
    }
}

extern "C" void kernel_launch(void* const* d_in, const int* in_sizes, int n_in,
                              void* d_out, int out_size, void* d_ws, size_t ws_size,
                              hipStream_t stream) {
    // Map inputs BY ELEMENT COUNT (all unique) — robust to positional order.
    const float* x  = (const float*)d_in[0];
    const void*  ei = d_in[1];
    const float* Wc = (const float*)d_in[2];
    const float* bc = (const float*)d_in[3];
    const float* Wl = (const float*)d_in[4];
    const float* bl = (const float*)d_in[5];
    for (int i = 0; i < n_in; i++) {
        switch (in_sizes[i]) {
            case N_NODES * IN_DIM:   x  = (const float*)d_in[i]; break;
            case 2 * N_EDGES:
            case 4 * N_EDGES:        ei = d_in[i]; break;
            case IN_DIM * HID:       Wc = (const float*)d_in[i]; break;
            case HID:                bc = (const float*)d_in[i]; break;
            case HID * 2:            Wl = (const float*)d_in[i]; break;
            case 2:                  bl = (const float*)d_in[i]; break;
            default: break;
        }
    }
    float* out = (float*)d_out;

    const int* src = (const int*)ei;            // edge_index[0] (int32, proven r2≡r3)
    const int* dst = (const int*)ei + N_EDGES;  // edge_index[1]

    char* ws = (char*)d_ws;
    size_t off = 0;
    unsigned short* gm    = (unsigned short*)(ws + off); off += (size_t)N_NODES * HID * 2;  // 12.8 MB
    float*    dinv        = (float*)(ws + off);    off += (size_t)N_NODES * 4;
    int*      row_start   = (int*)(ws + off);      off += (size_t)(N_NODES + 4) * 4;
    int*      bucketcnt   = (int*)(ws + off);      off += (size_t)(NB + 4) * 4;
    int*      bucket_base = (int*)(ws + off);      off += (size_t)(NB + 4) * 4;
    unsigned* gbuf        = (unsigned*)(ws + off); off += (size_t)NB * MAXPB * 4;     // 12.8 MB
    int*      srcs        = (int*)(ws + off);      off += (size_t)N_EDGES * 4;        // 6.4 MB

    hipMemsetAsync(bucketcnt, 0, (size_t)NB * 4, stream);
    k_bucket<<<BUCKET_BLOCKS, 512, 0, stream>>>(src, dst, bucketcnt, gbuf);
    k_scanB<<<1, 512, 0, stream>>>(bucketcnt, bucket_base);
    k_csr2<<<NB, 256, 0, stream>>>(gbuf, bucketcnt, bucket_base, row_start, dinv, srcs);
    k_gemm<<<N_NODES / 16, 256, 0, stream>>>(x, Wc, dinv, gm);
    k_aggr<<<(N_NODES + 15) / 16, 256, 0, stream>>>(gm, row_start, srcs, dinv, bc, Wl, bl, out);
}

// Round 2
// 183.804 us; speedup vs baseline: 1.2995x; 1.1421x over previous
//
#include <hip/hip_runtime.h>
#include <hip/hip_bf16.h>

#define N_NODES 100000
#define N_EDGES 1600000
#define IN_DIM 128
#define HID 64
#define NB ((N_NODES + 255) / 256)          // 391 buckets of 256 dst nodes
#define EPB 4096                            // edges per k_bucket block
#define BUCKET_BLOCKS ((N_EDGES + EPB - 1) / EPB)  // 391
#define MAXPB 8192                          // fixed gbuf region per bucket (mean 4092)

typedef __attribute__((ext_vector_type(8))) short bf16x8;
typedef __attribute__((ext_vector_type(4))) float f32x4;

// ---------------- threefry2x32, key = (0, 42) ----------------
__device__ __forceinline__ unsigned rotl32(unsigned x, unsigned r) {
    return (x << r) | (x >> (32u - r));
}

__device__ __forceinline__ void threefry2x32_k42(unsigned x0, unsigned x1,
                                                 unsigned& o0, unsigned& o1) {
    const unsigned ks0 = 0u;
    const unsigned ks1 = 42u;
    const unsigned ks2 = 0u ^ 42u ^ 0x1BD11BDAu;
    x0 += ks0; x1 += ks1;
    x0 += x1; x1 = rotl32(x1, 13); x1 ^= x0;
    x0 += x1; x1 = rotl32(x1, 15); x1 ^= x0;
    x0 += x1; x1 = rotl32(x1, 26); x1 ^= x0;
    x0 += x1; x1 = rotl32(x1, 6);  x1 ^= x0;
    x0 += ks1; x1 += ks2 + 1u;
    x0 += x1; x1 = rotl32(x1, 17); x1 ^= x0;
    x0 += x1; x1 = rotl32(x1, 29); x1 ^= x0;
    x0 += x1; x1 = rotl32(x1, 16); x1 ^= x0;
    x0 += x1; x1 = rotl32(x1, 24); x1 ^= x0;
    x0 += ks2; x1 += ks0 + 2u;
    x0 += x1; x1 = rotl32(x1, 13); x1 ^= x0;
    x0 += x1; x1 = rotl32(x1, 15); x1 ^= x0;
    x0 += x1; x1 = rotl32(x1, 26); x1 ^= x0;
    x0 += x1; x1 = rotl32(x1, 6);  x1 ^= x0;
    x0 += ks0; x1 += ks1 + 3u;
    x0 += x1; x1 = rotl32(x1, 17); x1 ^= x0;
    x0 += x1; x1 = rotl32(x1, 29); x1 ^= x0;
    x0 += x1; x1 = rotl32(x1, 16); x1 ^= x0;
    x0 += x1; x1 = rotl32(x1, 24); x1 ^= x0;
    x0 += ks1; x1 += ks2 + 4u;
    x0 += x1; x1 = rotl32(x1, 13); x1 ^= x0;
    x0 += x1; x1 = rotl32(x1, 15); x1 ^= x0;
    x0 += x1; x1 = rotl32(x1, 26); x1 ^= x0;
    x0 += x1; x1 = rotl32(x1, 6);  x1 ^= x0;
    x0 += ks2; x1 += ks0 + 5u;
    o0 = x0; o1 = x1;
}

__device__ __forceinline__ float bf2f(unsigned short u) {
    return __uint_as_float((unsigned)u << 16);
}
// low/high bf16 of a packed uint
__device__ __forceinline__ float bf2f_lo(unsigned u) {
    return __uint_as_float(u << 16);
}
__device__ __forceinline__ float bf2f_hi(unsigned u) {
    return __uint_as_float(u & 0xffff0000u);
}

// ---- phase 1: bucketed scatter into FIXED regions (no scan dependency) ----
// record = (c & 255) << 17 | r   (r < 2^17)
__global__ __launch_bounds__(512) void k_bucket(const int* __restrict__ src,
                                                const int* __restrict__ dst,
                                                int* __restrict__ bucketcnt,
                                                unsigned* __restrict__ gbuf) {
    __shared__ int cnt[512];
    __shared__ int off[512];
    __shared__ int cur[NB];
    __shared__ int gbase[NB];
    __shared__ unsigned buf[EPB];
    __shared__ unsigned short bkt[EPB];
    const int t = threadIdx.x;
    const int e0 = blockIdx.x * EPB;
    const int n = min(EPB, N_EDGES - e0);
    cnt[t] = 0;
    __syncthreads();
    unsigned myrec[EPB / 512];
    int myb[EPB / 512];
#pragma unroll
    for (int k = 0; k < EPB / 512; k++) {
        int e = e0 + k * 512 + t;
        if (e < N_EDGES) {
            int r = src[e];
            int c = dst[e];
            int b = c >> 8;
            myrec[k] = ((unsigned)(c & 255) << 17) | (unsigned)r;
            myb[k] = b;
            atomicAdd(&cnt[b], 1);
        } else {
            myb[k] = -1;
        }
    }
    __syncthreads();
    int own = cnt[t];
    for (int o = 1; o < 512; o <<= 1) {
        int v = (t >= o) ? cnt[t - o] : 0;
        __syncthreads();
        cnt[t] += v;
        __syncthreads();
    }
    off[t] = cnt[t] - own;  // exclusive prefix (records sorted by bucket in buf)
    if (t < NB) {
        cur[t] = off[t];
        gbase[t] = t * MAXPB + (own ? atomicAdd(&bucketcnt[t], own) : 0);
    }
    __syncthreads();
#pragma unroll
    for (int k = 0; k < EPB / 512; k++) {
        if (myb[k] >= 0) {
            int p = atomicAdd(&cur[myb[k]], 1);
            buf[p] = myrec[k];
            bkt[p] = (unsigned short)myb[k];
        }
    }
    __syncthreads();
    for (int j = t; j < n; j += 512) {
        int b = bkt[j];
        gbuf[gbase[b] + (j - off[b])] = buf[j];
    }
}

// ---- exclusive scan over NB bucket totals -> bucket_base ----
__global__ __launch_bounds__(512) void k_scanB(const int* __restrict__ bucketcnt,
                                               int* __restrict__ bucket_base) {
    __shared__ int s[512];
    int t = threadIdx.x;
    int own = (t < NB) ? bucketcnt[t] : 0;
    s[t] = own;
    __syncthreads();
    for (int o = 1; o < 512; o <<= 1) {
        int v = (t >= o) ? s[t - o] : 0;
        __syncthreads();
        s[t] += v;
        __syncthreads();
    }
    if (t < NB) bucket_base[t] = s[t] - own;
    if (t == 511) bucket_base[NB] = s[511];  // = N_EDGES
}

// ---- phase 2: per-bucket count + scan + row_start + dinv + distribute ----
__global__ __launch_bounds__(256) void k_csr2(const unsigned* __restrict__ gbuf,
                                              const int* __restrict__ bucketcnt,
                                              const int* __restrict__ bucket_base,
                                              int* __restrict__ row_start,
                                              float* __restrict__ dinv,
                                              int* __restrict__ srcs) {
    __shared__ unsigned lbuf[MAXPB];  // 32 KB
    __shared__ int lcnt[256];
    __shared__ int pre[256];
    __shared__ int cur[256];
    const int b = blockIdx.x, t = threadIdx.x;
    const int n = bucketcnt[b];
    const unsigned* reg = gbuf + (size_t)b * MAXPB;
    lcnt[t] = 0;
    for (int j = t; j < n; j += 256) lbuf[j] = reg[j];
    __syncthreads();
    for (int j = t; j < n; j += 256) atomicAdd(&lcnt[lbuf[j] >> 17], 1);
    __syncthreads();
    int my = lcnt[t];
    pre[t] = my;
    __syncthreads();
    for (int o = 1; o < 256; o <<= 1) {
        int v = (t >= o) ? pre[t - o] : 0;
        __syncthreads();
        pre[t] += v;
        __syncthreads();
    }
    const int gb = bucket_base[b];
    int base = gb + pre[t] - my;  // global exclusive prefix
    cur[t] = base;
    const int c = b * 256 + t;
    if (c < N_NODES) {
        row_start[c] = base;
        dinv[c] = rsqrtf((float)(my + 1));  // in-degree + self-loop
    }
    if (b == NB - 1 && t == 255) row_start[N_NODES] = gb + pre[255];
    __syncthreads();
    for (int j = t; j < n; j += 256) {
        unsigned rec = lbuf[j];
        int pos = atomicAdd(&cur[rec >> 17], 1);
        srcs[pos] = (int)(rec & 0x1FFFF);
    }
}

// ------ g = (x @ W_conv) * dinv[row], bf16 out — MFMA split-bf16 version ------
// 3-pass split: x=xh+xl, W=Wh+Wl (bf16 each); h = xh@Wh + xl@Wh + xh@Wl.
// Residual xl@Wl ~ 2^-16 relative => fp32-class accuracy.
// Block: 256 thr = 4 waves, 64 rows/block (16 rows/wave), N=64, K=128 per wave.
// mfma_f32_16x16x32_bf16: A-frag lane holds rows lane&15, k=(lane>>4)*8..+7;
// C/D: col=lane&15, row=(lane>>4)*4+reg (m89-verified mapping).
__global__ __launch_bounds__(256) void k_gemm(const float* __restrict__ x,
                                              const float* __restrict__ W,
                                              const float* __restrict__ dinv,
                                              unsigned short* __restrict__ gm) {
    // W^T split hi/lo in LDS. Stride 136 ushorts = 272 B: 16B-aligned rows,
    // delta-bank 4/lane on b128 reads -> 2-way conflict (free, m136).
    __shared__ unsigned short WtH[HID][136];
    __shared__ unsigned short WtL[HID][136];
    const int t = threadIdx.x;
    // stage: thread t -> n = t&63, k-range [(t>>6)*32, +32). Reads coalesced
    // (consecutive t = consecutive n at same k). Writes packed b32 (2 k/write).
    {
        const int n = t & 63;
        const int k0 = (t >> 6) * 32;
        for (int k = k0; k < k0 + 32; k += 2) {
            float w0 = W[(size_t)k * HID + n];
            float w1 = W[(size_t)(k + 1) * HID + n];
            unsigned short h0 = __bfloat16_as_ushort(__float2bfloat16(w0));
            unsigned short h1 = __bfloat16_as_ushort(__float2bfloat16(w1));
            unsigned short l0 = __bfloat16_as_ushort(__float2bfloat16(w0 - bf2f(h0)));
            unsigned short l1 = __bfloat16_as_ushort(__float2bfloat16(w1 - bf2f(h1)));
            *(unsigned*)&WtH[n][k] = (unsigned)h0 | ((unsigned)h1 << 16);
            *(unsigned*)&WtL[n][k] = (unsigned)l0 | ((unsigned)l1 << 16);
        }
    }
    __syncthreads();

    const int wave = t >> 6, lane = t & 63;
    const int row16 = lane & 15;   // A-frag row within tile / B-frag col
    const int kgrp = lane >> 4;    // k-subgroup
    const int browA = blockIdx.x * 64 + wave * 16;

    // ---- load x rows (fp32) and split into hi/lo bf16 A-fragments ----
    const int rA = min(browA + row16, N_NODES - 1);  // clamp tail reads
    const float* xr = x + (size_t)rA * IN_DIM + kgrp * 8;
    float xv[32];
#pragma unroll
    for (int ks = 0; ks < 4; ks++) {
        *(f32x4*)&xv[ks * 8]     = *(const f32x4*)(xr + ks * 32);
        *(f32x4*)&xv[ks * 8 + 4] = *(const f32x4*)(xr + ks * 32 + 4);
    }
    bf16x8 ah[4], al[4];
#pragma unroll
    for (int ks = 0; ks < 4; ks++) {
#pragma unroll
        for (int j = 0; j < 8; j++) {
            float v = xv[ks * 8 + j];
            unsigned short h = __bfloat16_as_ushort(__float2bfloat16(v));
            unsigned short l = __bfloat16_as_ushort(__float2bfloat16(v - bf2f(h)));
            ah[ks][j] = (short)h;
            al[ks][j] = (short)l;
        }
    }

    // ---- per-lane output rows + dinv (C layout: row=(lane>>4)*4+i) ----
    float dv[4];
    int orow[4];
#pragma unroll
    for (int i = 0; i < 4; i++) {
        orow[i] = browA + kgrp * 4 + i;
        dv[i] = dinv[min(orow[i], N_NODES - 1)];
    }

    // ---- 4 n-tiles of 16 cols ----
#pragma unroll
    for (int nt = 0; nt < 4; nt++) {
        const int n = nt * 16 + row16;
        bf16x8 bh[4], bl[4];
#pragma unroll
        for (int ks = 0; ks < 4; ks++) {
            bh[ks] = *(const bf16x8*)&WtH[n][ks * 32 + kgrp * 8];
            bl[ks] = *(const bf16x8*)&WtL[n][ks * 32 + kgrp * 8];
        }
        f32x4 acc = {0.f, 0.f, 0.f, 0.f};
#pragma unroll
        for (int ks = 0; ks < 4; ks++)
            acc = __builtin_amdgcn_mfma_f32_16x16x32_bf16(ah[ks], bh[ks], acc, 0, 0, 0);
#pragma unroll
        for (int ks = 0; ks < 4; ks++)
            acc = __builtin_amdgcn_mfma_f32_16x16x32_bf16(al[ks], bh[ks], acc, 0, 0, 0);
#pragma unroll
        for (int ks = 0; ks < 4; ks++)
            acc = __builtin_amdgcn_mfma_f32_16x16x32_bf16(ah[ks], bl[ks], acc, 0, 0, 0);
#pragma unroll
        for (int i = 0; i < 4; i++) {
            if (orow[i] < N_NODES) {
                float g = acc[i] * dv[i];
                gm[(size_t)orow[i] * HID + nt * 16 + row16] =
                    __bfloat16_as_ushort(__float2bfloat16(g));
            }
        }
    }
}

// ------- fused gather(bf16 g) + self + bias/relu/dropout + [64->2] matvec -------
// 16 lanes per dst node (4 dims/lane, dwordx2 gathers), 4 dsts per wave,
// 16 dsts per block. 4 independent edge streams/wave * unroll-8 => high MLP.
__global__ __launch_bounds__(256, 4) void k_aggr(const unsigned short* __restrict__ gm,
                                                 const int* __restrict__ row_start,
                                                 const int* __restrict__ srcs,
                                                 const float* __restrict__ dinv,
                                                 const float* __restrict__ bconv,
                                                 const float* __restrict__ Wlin,
                                                 const float* __restrict__ blin,
                                                 float* __restrict__ out) {
    const int c  = blockIdx.x * 16 + (threadIdx.x >> 4);  // dst node, group of 16 lanes
    const int d4 = threadIdx.x & 15;                      // dim quad: dims [4*d4, 4*d4+4)
    const int beg = row_start[c];
    const int end = row_start[c + 1];

    // self-loop term g[c] (accumulation order: self first, then j asc)
    const uint2 s0 = *(const uint2*)(gm + ((size_t)c << 6) + (d4 << 2));
    float a0 = bf2f_lo(s0.x), a1 = bf2f_hi(s0.x);
    float a2 = bf2f_lo(s0.y), a3 = bf2f_hi(s0.y);

    int j = beg;
    if (j + 8 <= end) {
        int r[8];
#pragma unroll
        for (int u = 0; u < 8; u++) r[u] = srcs[j + u];
        while (true) {
            uint2 w[8];
#pragma unroll
            for (int u = 0; u < 8; u++)
                w[u] = *(const uint2*)(gm + ((size_t)r[u] << 6) + (d4 << 2));
            j += 8;
            const bool more = (j + 8 <= end);
            int r2[8];
            if (more) {
#pragma unroll
                for (int u = 0; u < 8; u++) r2[u] = srcs[j + u];
            }
#pragma unroll
            for (int u = 0; u < 8; u++) {
                a0 += bf2f_lo(w[u].x); a1 += bf2f_hi(w[u].x);
                a2 += bf2f_lo(w[u].y); a3 += bf2f_hi(w[u].y);
            }
            if (!more) break;
#pragma unroll
            for (int u = 0; u < 8; u++) r[u] = r2[u];
        }
    }
    for (; j < end; j++) {
        const int r = srcs[j];
        const uint2 w = *(const uint2*)(gm + ((size_t)r << 6) + (d4 << 2));
        a0 += bf2f_lo(w.x); a1 += bf2f_hi(w.x);
        a2 += bf2f_lo(w.y); a3 += bf2f_hi(w.y);
    }

    const float dv = dinv[c];
    const float4 bc4 = *(const float4*)(bconv + (d4 << 2));
    float v0 = fmaxf(a0 * dv + bc4.x, 0.f);
    float v1 = fmaxf(a1 * dv + bc4.y, 0.f);
    float v2 = fmaxf(a2 * dv + bc4.z, 0.f);
    float v3 = fmaxf(a3 * dv + bc4.w, 0.f);

    // dropout: per-element threefry mapping i = c*64 + d
    const unsigned ib = (unsigned)(c * HID + (d4 << 2));
    unsigned o0, o1;
    threefry2x32_k42(0u, ib + 0u, o0, o1);
    v0 = ((o0 ^ o1) & 0x80000000u) ? 0.f : v0 * 2.f;
    threefry2x32_k42(0u, ib + 1u, o0, o1);
    v1 = ((o0 ^ o1) & 0x80000000u) ? 0.f : v1 * 2.f;
    threefry2x32_k42(0u, ib + 2u, o0, o1);
    v2 = ((o0 ^ o1) & 0x80000000u) ? 0.f : v2 * 2.f;
    threefry2x32_k42(0u, ib + 3u, o0, o1);
    v3 = ((o0 ^ o1) & 0x80000000u) ? 0.f : v3 * 2.f;

    // [64 -> 2] matvec partials: Wlin row-major [64][2]; lane covers rows 4*d4..4*d4+3
    const float4 wl0 = *(const float4*)(Wlin + (d4 << 3));      // rows 4d4, 4d4+1
    const float4 wl1 = *(const float4*)(Wlin + (d4 << 3) + 4);  // rows 4d4+2, 4d4+3
    float p0 = v0 * wl0.x + v1 * wl0.z + v2 * wl1.x + v3 * wl1.z;
    float p1 = v0 * wl0.y + v1 * wl0.w + v2 * wl1.y + v3 * wl1.w;

    // reduce across the 16 lanes of this dst group (aligned, so xor stays in-group)
#pragma unroll
    for (int off = 8; off; off >>= 1) {
        p0 += __shfl_xor(p0, off);
        p1 += __shfl_xor(p1, off);
    }
    if (d4 == 0) {
        *(float2*)(out + (size_t)c * 2) = make_float2(p0 + blin[0], p1 + blin[1]);
    }
}

extern "C" void kernel_launch(void* const* d_in, const int* in_sizes, int n_in,
                              void* d_out, int out_size, void* d_ws, size_t ws_size,
                              hipStream_t stream) {
    // Map inputs BY ELEMENT COUNT (all unique) — robust to positional order.
    const float* x  = (const float*)d_in[0];
    const void*  ei = d_in[1];
    const float* Wc = (const float*)d_in[2];
    const float* bc = (const float*)d_in[3];
    const float* Wl = (const float*)d_in[4];
    const float* bl = (const float*)d_in[5];
    for (int i = 0; i < n_in; i++) {
        switch (in_sizes[i]) {
            case N_NODES * IN_DIM:   x  = (const float*)d_in[i]; break;
            case 2 * N_EDGES:
            case 4 * N_EDGES:        ei = d_in[i]; break;
            case IN_DIM * HID:       Wc = (const float*)d_in[i]; break;
            case HID:                bc = (const float*)d_in[i]; break;
            case HID * 2:            Wl = (const float*)d_in[i]; break;
            case 2:                  bl = (const float*)d_in[i]; break;
            default: break;
        }
    }
    float* out = (float*)d_out;

    const int* src = (const int*)ei;            // edge_index[0] (int32, proven r2≡r3)
    const int* dst = (const int*)ei + N_EDGES;  // edge_index[1]

    char* ws = (char*)d_ws;
    size_t off = 0;
    unsigned short* gm    = (unsigned short*)(ws + off); off += (size_t)N_NODES * HID * 2;  // 12.8 MB
    float*    dinv        = (float*)(ws + off);    off += (size_t)N_NODES * 4;
    int*      row_start   = (int*)(ws + off);      off += (size_t)(N_NODES + 4) * 4;
    int*      bucketcnt   = (int*)(ws + off);      off += (size_t)(NB + 4) * 4;
    int*      bucket_base = (int*)(ws + off);      off += (size_t)(NB + 4) * 4;
    unsigned* gbuf        = (unsigned*)(ws + off); off += (size_t)NB * MAXPB * 4;     // 12.8 MB
    int*      srcs        = (int*)(ws + off);      off += (size_t)N_EDGES * 4;        // 6.4 MB

    hipMemsetAsync(bucketcnt, 0, (size_t)NB * 4, stream);
    k_bucket<<<BUCKET_BLOCKS, 512, 0, stream>>>(src, dst, bucketcnt, gbuf);
    k_scanB<<<1, 512, 0, stream>>>(bucketcnt, bucket_base);
    k_csr2<<<NB, 256, 0, stream>>>(gbuf, bucketcnt, bucket_base, row_start, dinv, srcs);
    k_gemm<<<(N_NODES + 63) / 64, 256, 0, stream>>>(x, Wc, dinv, gm);
    k_aggr<<<(N_NODES + 15) / 16, 256, 0, stream>>>(gm, row_start, srcs, dinv, bc, Wl, bl, out);
}